// Round 8
// baseline (195.981 us; speedup 1.0000x reference)
//
#include <hip/hip_runtime.h>
#include <hip/hip_bf16.h>

#define SEQ 4096
#define BSZ 2
#define NH 8
#define HD 64
#define DMODEL 512

typedef __bf16 bf16_t;
typedef __bf16 bf16x8 __attribute__((ext_vector_type(8)));
typedef __bf16 bf16x4 __attribute__((ext_vector_type(4)));
typedef float f32x4 __attribute__((ext_vector_type(4)));

__device__ __forceinline__ f32x4 mfma16(bf16x8 a, bf16x8 b, f32x4 c) {
    return __builtin_amdgcn_mfma_f32_16x16x32_bf16(a, b, c, 0, 0, 0);
}

__device__ __forceinline__ bf16x8 ld8(const bf16_t* p) {
    return *reinterpret_cast<const bf16x8*>(p);
}

__device__ __forceinline__ uint32_t pack2(bf16_t a, bf16_t b) {
    union { bf16_t h[2]; uint32_t u; } x;
    x.h[0] = a; x.h[1] = b;
    return x.u;
}

// async global->LDS DMA, 16 B/lane; data lands at lds base + lane*16
__device__ __forceinline__ void gl_lds16(const bf16_t* g, bf16_t* l) {
    __builtin_amdgcn_global_load_lds(
        (const __attribute__((address_space(1))) uint32_t*)g,
        (__attribute__((address_space(3))) uint32_t*)l,
        16, 0, 0);
}

// ---------------- cast fp32 -> bf16 weights + RoPE cos/sin table ----------------
// r20: fused RoPE table build. tab[s*32 + f] = {cos,sin} of angle for
// position s: f<16 -> t-rope freq f with idx s/V; f>=16 -> v-rope freq f-16
// with idx s%V. 4096x32 float2 = 1 MB, lives in the (dead until flash) Yb
// region. Deletes div + exp2f + sinf + cosf from gemm_qkv's epilogue.
// (verified r20: total 197 -> 183 us, flash control unchanged)
__global__ void cast_w(const float* __restrict__ wq, const float* __restrict__ wk,
                       const float* __restrict__ wv, const float* __restrict__ wo,
                       bf16_t* __restrict__ Wc, bf16_t* __restrict__ Wob,
                       float2* __restrict__ tab, const int* __restrict__ Vpar) {
    int i = blockIdx.x * blockDim.x + threadIdx.x;   // 0..262143 float4 groups
    int w = i >> 16, j = i & 65535;
    const float* src = (w == 0) ? wq : (w == 1) ? wk : (w == 2) ? wv : wo;
    bf16_t* dst = (w == 3) ? Wob : Wc + w * 262144;
    float4 v = reinterpret_cast<const float4*>(src)[j];
    bf16x4 o;
    o[0] = (bf16_t)v.x; o[1] = (bf16_t)v.y; o[2] = (bf16_t)v.z; o[3] = (bf16_t)v.w;
    reinterpret_cast<bf16x4*>(dst)[j] = o;

    if (i < SEQ * 32) {
        int s = i >> 5, f = i & 31;
        int Vv = Vpar[0];
        int tq = s / Vv;
        int vq = s - tq * Vv;
        float idx = (float)((f < 16) ? tq : vq);
        float invf = exp2f((float)(f & 15) * -0.8304820237218407f); // 10000^(-fidx/16)
        float ang = idx * invf;
        tab[i] = make_float2(__cosf(ang), __sinf(ang));
    }
}

// ---------------- GEMM1: fp32 A (x) + bf16 W, fused cast + RoPE epilogue ----------------
// A staged flash-V-style: float4 reg-prefetch -> cvt bf16 -> ds_write_b64 at
// loop top (before barrier); B staged via swizzle-free DMA. Dbuf, 1
// barrier/iter. r20: RoPE via precomputed cos/sin table (verified).
// r23: grid swapped to n-fastest (12, 64): 12 consecutive blocks share one
// 256 KB A-panel -> A stays hot in XCD L2 instead of 12 full re-streams of
// the 16.8 MB fp32 A (~200 MB from L3). Pure indexing change.
__global__ __launch_bounds__(256) void gemm_qkv(const float* __restrict__ A,
                                                const bf16_t* __restrict__ W,
                                                bf16_t* __restrict__ Qb,
                                                bf16_t* __restrict__ Kb,
                                                bf16_t* __restrict__ Vb,
                                                const float2* __restrict__ tab) {
    __shared__ bf16_t As[2 * 128 * 32];   // 16 KB
    __shared__ bf16_t Bs[2 * 128 * 32];   // 16 KB
    const int lane = threadIdx.x & 63;
    const int wid = threadIdx.x >> 6;
    const int c = lane & 15, quad = lane >> 4;
    const int wm = wid & 1, wn = wid >> 1;
    const int m0 = blockIdx.y * 128;      // r23: m on slow axis
    const int n0 = blockIdx.x * 128;      // r23: n on fast axis

    f32x4 acc[4][4];
#pragma unroll
    for (int i = 0; i < 4; i++)
#pragma unroll
        for (int j = 0; j < 4; j++) acc[i][j] = f32x4{0.f, 0.f, 0.f, 0.f};

    // B staging (DMA): wave covers rows [wid*32, wid*32+32) in 2 calls
    const int lrow = lane >> 2;
    const int lch = lane & 3;
    const bf16_t* Bg = W + (size_t)(n0 + wid * 32 + lrow) * 512 + lch * 8;
    const int w0 = (wid * 32) * 32;
    const int w1 = (wid * 32 + 16) * 32;

    // A staging (regs+cvt): lane covers row wid*32 + i*8 + (lane>>3),
    // cols (lane&7)*4 .. +3 (float4), i = 0..3
    const float* Ag32 = A + (size_t)(m0 + wid * 32 + (lane >> 3)) * 512 + (lane & 7) * 4;
    bf16_t* Aw = As + (wid * 32 + (lane >> 3)) * 32 + (lane & 7) * 4;

    // pre-loop: tile 0
    float4 ar[4];
#pragma unroll
    for (int i = 0; i < 4; i++)
        ar[i] = *reinterpret_cast<const float4*>(Ag32 + (size_t)i * 8 * 512);
    gl_lds16(Bg, Bs + w0);
    gl_lds16(Bg + 16 * 512, Bs + w1);

    for (int it = 0; it < 16; it++) {
        // write A(it) regs -> LDS buf[it&1] (cvt fp32->bf16)
        bf16_t* aw = Aw + (it & 1) * 4096;
#pragma unroll
        for (int i = 0; i < 4; i++) {
            bf16x4 c4;
            c4[0] = (bf16_t)ar[i].x; c4[1] = (bf16_t)ar[i].y;
            c4[2] = (bf16_t)ar[i].z; c4[3] = (bf16_t)ar[i].w;
            *reinterpret_cast<bf16x4*>(aw + i * 8 * 32) = c4;
        }

        __syncthreads();   // drains B-DMA(it); A writes visible; prev readers done

        if (it + 1 < 16) {
            int k0 = (it + 1) * 32;
            int bo = ((it + 1) & 1) * 4096;
            // A reg-loads issued BEFORE B-DMA so the A-write wait next iter
            // is a counted vmcnt (leaves B-DMA in flight until the barrier)
#pragma unroll
            for (int i = 0; i < 4; i++)
                ar[i] = *reinterpret_cast<const float4*>(Ag32 + (size_t)i * 8 * 512 + k0);
            gl_lds16(Bg + k0, Bs + bo + w0);
            gl_lds16(Bg + 16 * 512 + k0, Bs + bo + w1);
        }

        const bf16_t* Ab = As + (it & 1) * 4096;
        const bf16_t* Bb = Bs + (it & 1) * 4096;
        bf16x8 a[4], b[4];
#pragma unroll
        for (int i = 0; i < 4; i++) a[i] = ld8(&Ab[(wm * 64 + i * 16 + c) * 32 + quad * 8]);
#pragma unroll
        for (int j = 0; j < 4; j++) b[j] = ld8(&Bb[(wn * 64 + j * 16 + c) * 32 + quad * 8]);
        __builtin_amdgcn_s_setprio(1);
#pragma unroll
        for (int i = 0; i < 4; i++)
#pragma unroll
            for (int j = 0; j < 4; j++) acc[i][j] = mfma16(a[i], b[j], acc[i][j]);
        __builtin_amdgcn_s_setprio(0);
    }

    const float qs = 0.1803368801111204f;   // 0.125 * log2(e)
    const bool codd = (c & 1);

#pragma unroll
    for (int i = 0; i < 4; i++) {
        int mbase = m0 + wm * 64 + i * 16 + quad * 4;
#pragma unroll
        for (int j = 0; j < 4; j++) {
            int col = n0 + wn * 64 + j * 16 + c;
            int which = col >> 9;            // uniform per (wave, j)
            int h = (col >> 6) & 7;
            int d = col & 63;
            f32x4 v = acc[i][j];
            if (which < 2) {                 // rope Q / K (wave-uniform branch)
                int fo = ((d >= 32) ? 16 : 0) + ((d & 31) >> 1);
                f32x4 part;
#pragma unroll
                for (int r = 0; r < 4; r++) part[r] = __shfl_xor(v[r], 1, 64);
#pragma unroll
                for (int r = 0; r < 4; r++) {
                    int s = (mbase + r) & 4095;
                    float2 cs2 = tab[s * 32 + fo];
                    float xe = codd ? part[r] : v[r];
                    float xo = codd ? v[r] : part[r];
                    v[r] = codd ? (xe * cs2.y + xo * cs2.x) : (xe * cs2.x - xo * cs2.y);
                }
                if (which == 0) {
#pragma unroll
                    for (int r = 0; r < 4; r++) v[r] *= qs;
                }
            }
            bf16_t* dst = (which == 0) ? Qb : ((which == 1) ? Kb : Vb);

            // paired dword stores: even lane rows 0-1, odd lane rows 2-3
            float p0 = __shfl_xor(v[0], 1, 64);
            float p1 = __shfl_xor(v[1], 1, 64);
            float p2 = __shfl_xor(v[2], 1, 64);
            float p3 = __shfl_xor(v[3], 1, 64);
            uint32_t u0 = codd ? pack2((bf16_t)p2, (bf16_t)v[2])
                               : pack2((bf16_t)v[0], (bf16_t)p0);
            uint32_t u1 = codd ? pack2((bf16_t)p3, (bf16_t)v[3])
                               : pack2((bf16_t)v[1], (bf16_t)p1);
            int dcol = d & ~1;
            int m = mbase + (codd ? 2 : 0);
            {
                int b_ = m >> 12, s = m & 4095;
                *(uint32_t*)&dst[((size_t)(b_ * NH + h) * SEQ + s) * HD + dcol] = u0;
                m++;
                b_ = m >> 12; s = m & 4095;
                *(uint32_t*)&dst[((size_t)(b_ * NH + h) * SEQ + s) * HD + dcol] = u1;
            }
        }
    }
}

// ---------------- GEMM2: 128x64 tiles, dbuf staging ----------------
// r23: grid swapped to n-fastest (8, 64): 8 consecutive blocks share one
// 128-row Yb panel (A side) -> L2-hot instead of 8 full Yb re-streams.
__global__ __launch_bounds__(256) void gemm_out(const bf16_t* __restrict__ A,
                                                const bf16_t* __restrict__ W,
                                                float* __restrict__ out) {
    __shared__ bf16_t As[2 * 128 * 32];   // 16 KB
    __shared__ bf16_t Bs[2 * 64 * 32];    // 8 KB
    const int t = threadIdx.x;
    const int lane = t & 63;
    const int wid = t >> 6;
    const int c = lane & 15, quad = lane >> 4;
    const int m0 = blockIdx.y * 128;      // r23: m on slow axis
    const int n0 = blockIdx.x * 64;       // r23: n on fast axis

    f32x4 acc[2][4];
#pragma unroll
    for (int i = 0; i < 2; i++)
#pragma unroll
        for (int j = 0; j < 4; j++) acc[i][j] = f32x4{0.f, 0.f, 0.f, 0.f};

    const int lrow = lane >> 2;
    const int lch = lane & 3;
    const bf16_t* Ag = A + (size_t)(m0 + wid * 32 + lrow) * 512 + lch * 8;
    const bf16_t* Bg = W + (size_t)(n0 + wid * 16 + lrow) * 512 + lch * 8;
    const int aw0 = (wid * 32) * 32;
    const int aw1 = (wid * 32 + 16) * 32;
    const int bw = (wid * 16) * 32;

    gl_lds16(Ag, As + aw0);
    gl_lds16(Ag + 16 * 512, As + aw1);
    gl_lds16(Bg, Bs + bw);

    for (int it = 0; it < 16; it++) {
        __syncthreads();

        if (it + 1 < 16) {
            int k0 = (it + 1) * 32;
            int ao = ((it + 1) & 1) * 4096;
            int bo = ((it + 1) & 1) * 2048;
            gl_lds16(Ag + k0, As + ao + aw0);
            gl_lds16(Ag + 16 * 512 + k0, As + ao + aw1);
            gl_lds16(Bg + k0, Bs + bo + bw);
        }

        const bf16_t* Ab = As + (it & 1) * 4096;
        const bf16_t* Bb = Bs + (it & 1) * 2048;
        bf16x8 a[2], b[4];
#pragma unroll
        for (int i = 0; i < 2; i++) a[i] = ld8(&Ab[(wid * 32 + i * 16 + c) * 32 + quad * 8]);
#pragma unroll
        for (int j = 0; j < 4; j++) b[j] = ld8(&Bb[(j * 16 + c) * 32 + quad * 8]);
        __builtin_amdgcn_s_setprio(1);
#pragma unroll
        for (int i = 0; i < 2; i++)
#pragma unroll
            for (int j = 0; j < 4; j++) acc[i][j] = mfma16(a[i], b[j], acc[i][j]);
        __builtin_amdgcn_s_setprio(0);
    }

#pragma unroll
    for (int i = 0; i < 2; i++) {
        int mbase = m0 + wid * 32 + i * 16 + quad * 4;
#pragma unroll
        for (int j = 0; j < 4; j++) {
            int col = n0 + j * 16 + c;
#pragma unroll
            for (int r = 0; r < 4; r++)
                out[(size_t)(mbase + r) * DMODEL + col] = acc[i][j][r];
        }
    }
}

// ---------------- Flash attention (r23 = exact r19 core, verified 80.8 us) ----------------
// 1D grid of 512; bh = id & 15 so id mod 8 == bh mod 8 -> one head's KV per
// XCD L2. Core = r12: K via swizzled-source DMA dbuf, V reg-prefetch +
// transposed ds_write dbuf, 1 barrier/iter, exp2-domain softmax without
// max-subtraction. 2 waves/SIMD (grid-bound).
// r17a: vr loads before K-DMA in prefetch (counted vmcnt, verified −7%).
// r17b: s_setprio(1) around MFMA clusters (verified, part of the −7%).
// r18: row-sum on the MFMA pipe (ones-MFMA into accl; verified −8%).
// r19: 4kvx8d V-stage, 8 ds_write_b64 (verified −7%; 87.0 -> 80.8 us).
// r21 FAILED (K-frag preload -> spills, 104 us). r22 FAILED (split exp ->
//   +4 VGPR +1 MB spill writes, 84.2 us). EXP-overlap CLOSED: the r19
//   schedule is on the register-allocator knife edge; any added liveness
//   (even "zero-reg" splits) spills. Do not touch the softmax structure.
__global__ __launch_bounds__(256, 2) void flash_attn(const bf16_t* __restrict__ Q,
                                                     const bf16_t* __restrict__ K,
                                                     const bf16_t* __restrict__ V,
                                                     bf16_t* __restrict__ Y) {
    // per pair 32768 B: K buf0 8K | K buf1 8K | V^T buf0 8K | V^T buf1 8K
    __shared__ __align__(16) unsigned char smem[65536];

    const int t = threadIdx.x;
    const int lane = t & 63;
    const int c = lane & 15, quad = lane >> 4;
    const int wid = t >> 6;            // 0..3
    const int w = wid & 1;             // q-wave id == K-stage half id
    const int pr = wid >> 1;           // kv pair 0/1
    const int bh = blockIdx.x & 15;    // XCD-affinity: id%8 == bh%8
    const int qx = blockIdx.x >> 4;
    const int qw = qx * 128 + w * 64;

    size_t base = (size_t)bh * SEQ * HD;
    const bf16_t* Qp = Q + base;
    const bf16_t* Vp = V + base + (size_t)pr * 2048 * HD;

    unsigned char* pairBase = smem + pr * 32768;

    // K DMA swizzled source pointers: wave w stages tile rows [w*32, w*32+32)
    const bf16_t* Kpb = K + base + (size_t)pr * 2048 * HD;
    int srcOff = w * 4096 + ((lane >> 3) * 128) +
                 (((lane & 7) ^ ((lane >> 3) & 3)) * 16);
    const bf16_t* kE = (const bf16_t*)((const unsigned char*)Kpb + srcOff);
    const bf16_t* kO = (const bf16_t*)((const unsigned char*)Kpb + (srcOff ^ 64));

    bf16x8 qf[4][2];
#pragma unroll
    for (int qt = 0; qt < 4; qt++)
#pragma unroll
        for (int ks = 0; ks < 2; ks++)
            qf[qt][ks] = ld8(Qp + (size_t)(qw + qt * 16 + c) * HD + ks * 32 + quad * 8);

    f32x4 acc[4][4];
#pragma unroll
    for (int qt = 0; qt < 4; qt++)
#pragma unroll
        for (int dt = 0; dt < 4; dt++) acc[qt][dt] = f32x4{0.f, 0.f, 0.f, 0.f};
    f32x4 accl[4];
#pragma unroll
    for (int qt = 0; qt < 4; qt++) accl[qt] = f32x4{0.f, 0.f, 0.f, 0.f};
    bf16x8 onesv;
#pragma unroll
    for (int j = 0; j < 8; j++) onesv[j] = (bf16_t)1.0f;

    // V staging (pair's 128 threads): rows kva..kva+3, d in [dc8, dc8+8)
    const int tp = t & 127;
    const int kva = 4 * (tp & 15);
    const int dc8 = 8 * (tp >> 4);

    // pre-loop: V tile 0 into regs (issued first), K tile 0 DMA into buf0
    bf16x8 vr0 = ld8(Vp + (size_t)(kva + 0) * HD + dc8);
    bf16x8 vr1 = ld8(Vp + (size_t)(kva + 1) * HD + dc8);
    bf16x8 vr2 = ld8(Vp + (size_t)(kva + 2) * HD + dc8);
    bf16x8 vr3 = ld8(Vp + (size_t)(kva + 3) * HD + dc8);
    {
        bf16_t* dst = (bf16_t*)(pairBase + w * 4096);
#pragma unroll
        for (int i = 0; i < 4; i++)
            gl_lds16(((i & 1) ? kO : kE) + i * 512, dst + i * 512);
        kE += 4096; kO += 4096;
    }

    for (int kt = 0; kt < 32; kt++) {
        uint32_t* vt = (uint32_t*)(pairBase + 16384 + (kt & 1) * 8192);

        // V transpose+swizzle stage for tile kt: one b64 per d row
#pragma unroll
        for (int j = 0; j < 8; j++) {
            int d = dc8 + j;
            int sv = (d & 7) ^ ((d >> 3) & 7);
            int col = ((((kva >> 3) ^ sv) & 7) << 2) + ((kva >> 1) & 3);
            uint2 u;
            u.x = pack2(vr0[j], vr1[j]);     // kv kva, kva+1
            u.y = pack2(vr2[j], vr3[j]);     // kv kva+2, kva+3
            *reinterpret_cast<uint2*>(&vt[d * 32 + col]) = u;
        }

        __syncthreads();   // drains K-DMA(kt), V writes visible, prev readers done

        // prefetch tile kt+1: V into regs FIRST (so next V-write waits
        // vmcnt(4), not 0), then K via DMA into other buf
        if (kt + 1 < 32) {
            int kv0n = (kt + 1) * 64;
            vr0 = ld8(Vp + (size_t)(kv0n + kva + 0) * HD + dc8);
            vr1 = ld8(Vp + (size_t)(kv0n + kva + 1) * HD + dc8);
            vr2 = ld8(Vp + (size_t)(kv0n + kva + 2) * HD + dc8);
            vr3 = ld8(Vp + (size_t)(kv0n + kva + 3) * HD + dc8);
            bf16_t* dst = (bf16_t*)(pairBase + ((kt + 1) & 1) * 8192 + w * 4096);
#pragma unroll
            for (int i = 0; i < 4; i++)
                gl_lds16(((i & 1) ? kO : kE) + i * 512, dst + i * 512);
            kE += 4096; kO += 4096;
        }

        const uint4* kl = (const uint4*)(pairBase + (kt & 1) * 8192);

        // S^T = K*Q^T, kv-permuted rows
        f32x4 st[4][4];
        __builtin_amdgcn_s_setprio(1);
#pragma unroll
        for (int n = 0; n < 4; n++) {
            int kvr = (n >> 1) * 32 + ((c >> 2) * 8) + ((n & 1) * 4) + (c & 3);
            int sk = (kvr & 3) | (((kvr >> 3) & 1) << 2);
            bf16x8 k0 = *reinterpret_cast<const bf16x8*>(&kl[kvr * 8 + (quad ^ sk)]);
            bf16x8 k1 = *reinterpret_cast<const bf16x8*>(&kl[kvr * 8 + ((4 + quad) ^ sk)]);
#pragma unroll
            for (int qt = 0; qt < 4; qt++) {
                f32x4 z = f32x4{0.f, 0.f, 0.f, 0.f};
                z = mfma16(k0, qf[qt][0], z);
                z = mfma16(k1, qf[qt][1], z);
                st[qt][n] = z;
            }
        }
        __builtin_amdgcn_s_setprio(0);

        // softmax without max-subtraction (exp2 domain); no scalar row-sum —
        // the sum rides the MFMA pipe below (ones-MFMA into accl)
        bf16x8 pf[4][2];
#pragma unroll
        for (int qt = 0; qt < 4; qt++) {
            bf16x8 f0, f1;
#pragma unroll
            for (int j = 0; j < 8; j++) {
                f0[j] = (bf16_t)__builtin_amdgcn_exp2f(st[qt][(j >> 2)][j & 3]);
                f1[j] = (bf16_t)__builtin_amdgcn_exp2f(st[qt][2 + (j >> 2)][j & 3]);
            }
            pf[qt][0] = f0;
            pf[qt][1] = f1;
        }

        // O^T += V^T * P^T ; accl += ones * P^T (row-sum on MFMA pipe)
        __builtin_amdgcn_s_setprio(1);
#pragma unroll
        for (int dt = 0; dt < 4; dt++) {
            int d = dt * 16 + c;
            int sv = (d & 7) ^ ((d >> 3) & 7);
            bf16x8 v0f = *reinterpret_cast<const bf16x8*>(&vt[d * 32 + ((quad ^ sv) & 7) * 4]);
            bf16x8 v1f = *reinterpret_cast<const bf16x8*>(&vt[d * 32 + (((4 + quad) ^ sv) & 7) * 4]);
#pragma unroll
            for (int qt = 0; qt < 4; qt++) {
                acc[qt][dt] = mfma16(v0f, pf[qt][0], acc[qt][dt]);
                acc[qt][dt] = mfma16(v1f, pf[qt][1], acc[qt][dt]);
            }
        }
#pragma unroll
        for (int qt = 0; qt < 4; qt++) {
            accl[qt] = mfma16(onesv, pf[qt][0], accl[qt]);
            accl[qt] = mfma16(onesv, pf[qt][1], accl[qt]);
        }
        __builtin_amdgcn_s_setprio(0);
    }

    // every row of accl[qt] equals the kv-sum for q col c: no shfl needed
    float lred[4];
#pragma unroll
    for (int qt = 0; qt < 4; qt++) lred[qt] = accl[qt][0];

    // in-block pair-combine via LDS overlay
    __syncthreads();
    float* Ox = (float*)smem;
    float* Lx = (float*)(smem + 128 * 68 * 4);

    if (pr == 1) {
#pragma unroll
        for (int qt = 0; qt < 4; qt++) {
            int ql = w * 64 + qt * 16 + c;
#pragma unroll
            for (int dt = 0; dt < 4; dt++)
                *reinterpret_cast<f32x4*>(&Ox[ql * 68 + dt * 16 + quad * 4]) = acc[qt][dt];
            if (quad == 0) Lx[ql] = lred[qt];
        }
    }
    __syncthreads();
    if (pr == 0) {
        int b_ = bh >> 3, h = bh & 7;
#pragma unroll
        for (int qt = 0; qt < 4; qt++) {
            int ql = w * 64 + qt * 16 + c;
            float inv_l = 1.0f / (lred[qt] + Lx[ql]);
            int srow = qw + qt * 16 + c;
            bf16_t* yrow = Y + (size_t)(b_ * SEQ + srow) * DMODEL + h * HD;
#pragma unroll
            for (int dt = 0; dt < 4; dt++) {
                f32x4 o4 = acc[qt][dt] + *reinterpret_cast<const f32x4*>(&Ox[ql * 68 + dt * 16 + quad * 4]);
                bf16x4 o;
#pragma unroll
                for (int r = 0; r < 4; r++) o[r] = (bf16_t)(o4[r] * inv_l);
                *reinterpret_cast<bf16x4*>(yrow + dt * 16 + quad * 4) = o;
            }
        }
    }
}

extern "C" void kernel_launch(void* const* d_in, const int* in_sizes, int n_in,
                              void* d_out, int out_size, void* d_ws, size_t ws_size,
                              hipStream_t stream) {
    (void)in_sizes; (void)n_in; (void)out_size; (void)ws_size;
    const float* x  = (const float*)d_in[0];
    const float* Wq = (const float*)d_in[1];
    const float* Wk = (const float*)d_in[2];
    const float* Wv = (const float*)d_in[3];
    const float* Wo = (const float*)d_in[4];
    const int*   Vp = (const int*)d_in[6];
    float* out = (float*)d_out;

    bf16_t* ws  = (bf16_t*)d_ws;
    bf16_t* Wc  = ws;                    // [Wq|Wk|Wv] 3*512*512
    bf16_t* Wob = Wc  + 786432;          // 512*512
    bf16_t* Qb  = Wob + 262144;
    bf16_t* Kb  = Qb  + 4194304;
    bf16_t* Vb  = Kb  + 4194304;
    bf16_t* Yb  = Vb  + 4194304;
    // RoPE table overlays Yb (dead until flash_attn writes Y): 4096*32*8 B = 1 MB
    float2* tab = (float2*)Yb;

    cast_w<<<1024, 256, 0, stream>>>(Wq, Wk, Wv, Wo, Wc, Wob, tab, Vp);

    // r23: n-fastest grids for A-panel L2 reuse
    gemm_qkv<<<dim3(12, 64), 256, 0, stream>>>(x, Wc, Qb, Kb, Vb, tab);

    flash_attn<<<512, 256, 0, stream>>>(Qb, Kb, Vb, Yb);

    gemm_out<<<dim3(8, 64), 256, 0, stream>>>(Yb, Wob, out);
}

// Round 9
// 181.215 us; speedup vs baseline: 1.0815x; 1.0815x over previous
//
#include <hip/hip_runtime.h>
#include <hip/hip_bf16.h>

#define SEQ 4096
#define BSZ 2
#define NH 8
#define HD 64
#define DMODEL 512

typedef __bf16 bf16_t;
typedef __bf16 bf16x8 __attribute__((ext_vector_type(8)));
typedef __bf16 bf16x4 __attribute__((ext_vector_type(4)));
typedef float f32x4 __attribute__((ext_vector_type(4)));

__device__ __forceinline__ f32x4 mfma16(bf16x8 a, bf16x8 b, f32x4 c) {
    return __builtin_amdgcn_mfma_f32_16x16x32_bf16(a, b, c, 0, 0, 0);
}

__device__ __forceinline__ bf16x8 ld8(const bf16_t* p) {
    return *reinterpret_cast<const bf16x8*>(p);
}

__device__ __forceinline__ uint32_t pack2(bf16_t a, bf16_t b) {
    union { bf16_t h[2]; uint32_t u; } x;
    x.h[0] = a; x.h[1] = b;
    return x.u;
}

// async global->LDS DMA, 16 B/lane; data lands at lds base + lane*16
__device__ __forceinline__ void gl_lds16(const bf16_t* g, bf16_t* l) {
    __builtin_amdgcn_global_load_lds(
        (const __attribute__((address_space(1))) uint32_t*)g,
        (__attribute__((address_space(3))) uint32_t*)l,
        16, 0, 0);
}

// ---------------- cast fp32 -> bf16 weights + RoPE cos/sin table ----------------
// r20: fused RoPE table build. tab[s*32 + f] = {cos,sin} of angle for
// position s: f<16 -> t-rope freq f with idx s/V; f>=16 -> v-rope freq f-16
// with idx s%V. 4096x32 float2 = 1 MB, lives in the (dead until flash) Yb
// region. Deletes div + exp2f + sinf + cosf from gemm_qkv's epilogue.
// (verified r20: total 197 -> 183 us, flash control unchanged)
__global__ void cast_w(const float* __restrict__ wq, const float* __restrict__ wk,
                       const float* __restrict__ wv, const float* __restrict__ wo,
                       bf16_t* __restrict__ Wc, bf16_t* __restrict__ Wob,
                       float2* __restrict__ tab, const int* __restrict__ Vpar) {
    int i = blockIdx.x * blockDim.x + threadIdx.x;   // 0..262143 float4 groups
    int w = i >> 16, j = i & 65535;
    const float* src = (w == 0) ? wq : (w == 1) ? wk : (w == 2) ? wv : wo;
    bf16_t* dst = (w == 3) ? Wob : Wc + w * 262144;
    float4 v = reinterpret_cast<const float4*>(src)[j];
    bf16x4 o;
    o[0] = (bf16_t)v.x; o[1] = (bf16_t)v.y; o[2] = (bf16_t)v.z; o[3] = (bf16_t)v.w;
    reinterpret_cast<bf16x4*>(dst)[j] = o;

    if (i < SEQ * 32) {
        int s = i >> 5, f = i & 31;
        int Vv = Vpar[0];
        int tq = s / Vv;
        int vq = s - tq * Vv;
        float idx = (float)((f < 16) ? tq : vq);
        float invf = exp2f((float)(f & 15) * -0.8304820237218407f); // 10000^(-fidx/16)
        float ang = idx * invf;
        tab[i] = make_float2(__cosf(ang), __sinf(ang));
    }
}

// ---------------- GEMM1: fp32 A (x) + bf16 W, fused cast + RoPE epilogue ----------------
// A staged flash-V-style: float4 reg-prefetch -> cvt bf16 -> ds_write_b64 at
// loop top (before barrier); B staged via swizzle-free DMA. Dbuf, 1
// barrier/iter. r20: RoPE via precomputed cos/sin table (verified).
// r24: grid REVERTED to m-fast (64,12) — the r23 n-fast swap cost ~13 us
// (non-flash 101 -> 114.6). m-fast keeps one hot 128 KB B-panel per XCD and
// streams A (L3-resident); n-fast made each XCD hold multiple A-panels.
// DO NOT re-attempt epilogue/grid micro-edits here without gemm counters:
// r18/r19/r23 all regressed 11-14 us on "should-be-neutral" changes.
__global__ __launch_bounds__(256) void gemm_qkv(const float* __restrict__ A,
                                                const bf16_t* __restrict__ W,
                                                bf16_t* __restrict__ Qb,
                                                bf16_t* __restrict__ Kb,
                                                bf16_t* __restrict__ Vb,
                                                const float2* __restrict__ tab) {
    __shared__ bf16_t As[2 * 128 * 32];   // 16 KB
    __shared__ bf16_t Bs[2 * 128 * 32];   // 16 KB
    const int lane = threadIdx.x & 63;
    const int wid = threadIdx.x >> 6;
    const int c = lane & 15, quad = lane >> 4;
    const int wm = wid & 1, wn = wid >> 1;
    const int m0 = blockIdx.x * 128;
    const int n0 = blockIdx.y * 128;

    f32x4 acc[4][4];
#pragma unroll
    for (int i = 0; i < 4; i++)
#pragma unroll
        for (int j = 0; j < 4; j++) acc[i][j] = f32x4{0.f, 0.f, 0.f, 0.f};

    // B staging (DMA): wave covers rows [wid*32, wid*32+32) in 2 calls
    const int lrow = lane >> 2;
    const int lch = lane & 3;
    const bf16_t* Bg = W + (size_t)(n0 + wid * 32 + lrow) * 512 + lch * 8;
    const int w0 = (wid * 32) * 32;
    const int w1 = (wid * 32 + 16) * 32;

    // A staging (regs+cvt): lane covers row wid*32 + i*8 + (lane>>3),
    // cols (lane&7)*4 .. +3 (float4), i = 0..3
    const float* Ag32 = A + (size_t)(m0 + wid * 32 + (lane >> 3)) * 512 + (lane & 7) * 4;
    bf16_t* Aw = As + (wid * 32 + (lane >> 3)) * 32 + (lane & 7) * 4;

    // pre-loop: tile 0
    float4 ar[4];
#pragma unroll
    for (int i = 0; i < 4; i++)
        ar[i] = *reinterpret_cast<const float4*>(Ag32 + (size_t)i * 8 * 512);
    gl_lds16(Bg, Bs + w0);
    gl_lds16(Bg + 16 * 512, Bs + w1);

    for (int it = 0; it < 16; it++) {
        // write A(it) regs -> LDS buf[it&1] (cvt fp32->bf16)
        bf16_t* aw = Aw + (it & 1) * 4096;
#pragma unroll
        for (int i = 0; i < 4; i++) {
            bf16x4 c4;
            c4[0] = (bf16_t)ar[i].x; c4[1] = (bf16_t)ar[i].y;
            c4[2] = (bf16_t)ar[i].z; c4[3] = (bf16_t)ar[i].w;
            *reinterpret_cast<bf16x4*>(aw + i * 8 * 32) = c4;
        }

        __syncthreads();   // drains B-DMA(it); A writes visible; prev readers done

        if (it + 1 < 16) {
            int k0 = (it + 1) * 32;
            int bo = ((it + 1) & 1) * 4096;
            // A reg-loads issued BEFORE B-DMA so the A-write wait next iter
            // is a counted vmcnt (leaves B-DMA in flight until the barrier)
#pragma unroll
            for (int i = 0; i < 4; i++)
                ar[i] = *reinterpret_cast<const float4*>(Ag32 + (size_t)i * 8 * 512 + k0);
            gl_lds16(Bg + k0, Bs + bo + w0);
            gl_lds16(Bg + 16 * 512 + k0, Bs + bo + w1);
        }

        const bf16_t* Ab = As + (it & 1) * 4096;
        const bf16_t* Bb = Bs + (it & 1) * 4096;
        bf16x8 a[4], b[4];
#pragma unroll
        for (int i = 0; i < 4; i++) a[i] = ld8(&Ab[(wm * 64 + i * 16 + c) * 32 + quad * 8]);
#pragma unroll
        for (int j = 0; j < 4; j++) b[j] = ld8(&Bb[(wn * 64 + j * 16 + c) * 32 + quad * 8]);
        __builtin_amdgcn_s_setprio(1);
#pragma unroll
        for (int i = 0; i < 4; i++)
#pragma unroll
            for (int j = 0; j < 4; j++) acc[i][j] = mfma16(a[i], b[j], acc[i][j]);
        __builtin_amdgcn_s_setprio(0);
    }

    const float qs = 0.1803368801111204f;   // 0.125 * log2(e)
    const bool codd = (c & 1);

#pragma unroll
    for (int i = 0; i < 4; i++) {
        int mbase = m0 + wm * 64 + i * 16 + quad * 4;
#pragma unroll
        for (int j = 0; j < 4; j++) {
            int col = n0 + wn * 64 + j * 16 + c;
            int which = col >> 9;            // uniform per (wave, j)
            int h = (col >> 6) & 7;
            int d = col & 63;
            f32x4 v = acc[i][j];
            if (which < 2) {                 // rope Q / K (wave-uniform branch)
                int fo = ((d >= 32) ? 16 : 0) + ((d & 31) >> 1);
                f32x4 part;
#pragma unroll
                for (int r = 0; r < 4; r++) part[r] = __shfl_xor(v[r], 1, 64);
#pragma unroll
                for (int r = 0; r < 4; r++) {
                    int s = (mbase + r) & 4095;
                    float2 cs2 = tab[s * 32 + fo];
                    float xe = codd ? part[r] : v[r];
                    float xo = codd ? v[r] : part[r];
                    v[r] = codd ? (xe * cs2.y + xo * cs2.x) : (xe * cs2.x - xo * cs2.y);
                }
                if (which == 0) {
#pragma unroll
                    for (int r = 0; r < 4; r++) v[r] *= qs;
                }
            }
            bf16_t* dst = (which == 0) ? Qb : ((which == 1) ? Kb : Vb);

            // paired dword stores: even lane rows 0-1, odd lane rows 2-3
            float p0 = __shfl_xor(v[0], 1, 64);
            float p1 = __shfl_xor(v[1], 1, 64);
            float p2 = __shfl_xor(v[2], 1, 64);
            float p3 = __shfl_xor(v[3], 1, 64);
            uint32_t u0 = codd ? pack2((bf16_t)p2, (bf16_t)v[2])
                               : pack2((bf16_t)v[0], (bf16_t)p0);
            uint32_t u1 = codd ? pack2((bf16_t)p3, (bf16_t)v[3])
                               : pack2((bf16_t)v[1], (bf16_t)p1);
            int dcol = d & ~1;
            int m = mbase + (codd ? 2 : 0);
            {
                int b_ = m >> 12, s = m & 4095;
                *(uint32_t*)&dst[((size_t)(b_ * NH + h) * SEQ + s) * HD + dcol] = u0;
                m++;
                b_ = m >> 12; s = m & 4095;
                *(uint32_t*)&dst[((size_t)(b_ * NH + h) * SEQ + s) * HD + dcol] = u1;
            }
        }
    }
}

// ---------------- GEMM2: 128x64 tiles, dbuf staging, grid (64,8) ----------------
// r24: grid reverted to m-fast (64,8) — see gemm_qkv note.
__global__ __launch_bounds__(256) void gemm_out(const bf16_t* __restrict__ A,
                                                const bf16_t* __restrict__ W,
                                                float* __restrict__ out) {
    __shared__ bf16_t As[2 * 128 * 32];   // 16 KB
    __shared__ bf16_t Bs[2 * 64 * 32];    // 8 KB
    const int t = threadIdx.x;
    const int lane = t & 63;
    const int wid = t >> 6;
    const int c = lane & 15, quad = lane >> 4;
    const int m0 = blockIdx.x * 128;
    const int n0 = blockIdx.y * 64;

    f32x4 acc[2][4];
#pragma unroll
    for (int i = 0; i < 2; i++)
#pragma unroll
        for (int j = 0; j < 4; j++) acc[i][j] = f32x4{0.f, 0.f, 0.f, 0.f};

    const int lrow = lane >> 2;
    const int lch = lane & 3;
    const bf16_t* Ag = A + (size_t)(m0 + wid * 32 + lrow) * 512 + lch * 8;
    const bf16_t* Bg = W + (size_t)(n0 + wid * 16 + lrow) * 512 + lch * 8;
    const int aw0 = (wid * 32) * 32;
    const int aw1 = (wid * 32 + 16) * 32;
    const int bw = (wid * 16) * 32;

    gl_lds16(Ag, As + aw0);
    gl_lds16(Ag + 16 * 512, As + aw1);
    gl_lds16(Bg, Bs + bw);

    for (int it = 0; it < 16; it++) {
        __syncthreads();

        if (it + 1 < 16) {
            int k0 = (it + 1) * 32;
            int ao = ((it + 1) & 1) * 4096;
            int bo = ((it + 1) & 1) * 2048;
            gl_lds16(Ag + k0, As + ao + aw0);
            gl_lds16(Ag + 16 * 512 + k0, As + ao + aw1);
            gl_lds16(Bg + k0, Bs + bo + bw);
        }

        const bf16_t* Ab = As + (it & 1) * 4096;
        const bf16_t* Bb = Bs + (it & 1) * 2048;
        bf16x8 a[2], b[4];
#pragma unroll
        for (int i = 0; i < 2; i++) a[i] = ld8(&Ab[(wid * 32 + i * 16 + c) * 32 + quad * 8]);
#pragma unroll
        for (int j = 0; j < 4; j++) b[j] = ld8(&Bb[(j * 16 + c) * 32 + quad * 8]);
        __builtin_amdgcn_s_setprio(1);
#pragma unroll
        for (int i = 0; i < 2; i++)
#pragma unroll
            for (int j = 0; j < 4; j++) acc[i][j] = mfma16(a[i], b[j], acc[i][j]);
        __builtin_amdgcn_s_setprio(0);
    }

#pragma unroll
    for (int i = 0; i < 2; i++) {
        int mbase = m0 + wid * 32 + i * 16 + quad * 4;
#pragma unroll
        for (int j = 0; j < 4; j++) {
            int col = n0 + j * 16 + c;
#pragma unroll
            for (int r = 0; r < 4; r++)
                out[(size_t)(mbase + r) * DMODEL + col] = acc[i][j][r];
        }
    }
}

// ---------------- Flash attention (r19 core, verified 80.8-81.8 us) ----------------
// 1D grid of 512; bh = id & 15 so id mod 8 == bh mod 8 -> one head's KV per
// XCD L2. Core = r12: K via swizzled-source DMA dbuf, V reg-prefetch +
// transposed ds_write dbuf, 1 barrier/iter, exp2-domain softmax without
// max-subtraction. 2 waves/SIMD (grid-bound).
// r17a: vr loads before K-DMA in prefetch (counted vmcnt, verified −7%).
// r17b: s_setprio(1) around MFMA clusters (verified, part of the −7%).
// r18: row-sum on the MFMA pipe (ones-MFMA into accl; verified −8%).
// r19: 4kvx8d V-stage, 8 ds_write_b64 (verified −7%; 87.0 -> 80.8 us).
// r21 FAILED (K-frag preload -> spills, 104 us). r22 FAILED (split exp ->
//   +4 VGPR +1 MB spill writes, 84.2 us). EXP-overlap CLOSED: the r19
//   schedule is on the register-allocator knife edge; any added liveness
//   (even "zero-reg" splits) spills. Do not touch the softmax structure.
__global__ __launch_bounds__(256, 2) void flash_attn(const bf16_t* __restrict__ Q,
                                                     const bf16_t* __restrict__ K,
                                                     const bf16_t* __restrict__ V,
                                                     bf16_t* __restrict__ Y) {
    // per pair 32768 B: K buf0 8K | K buf1 8K | V^T buf0 8K | V^T buf1 8K
    __shared__ __align__(16) unsigned char smem[65536];

    const int t = threadIdx.x;
    const int lane = t & 63;
    const int c = lane & 15, quad = lane >> 4;
    const int wid = t >> 6;            // 0..3
    const int w = wid & 1;             // q-wave id == K-stage half id
    const int pr = wid >> 1;           // kv pair 0/1
    const int bh = blockIdx.x & 15;    // XCD-affinity: id%8 == bh%8
    const int qx = blockIdx.x >> 4;
    const int qw = qx * 128 + w * 64;

    size_t base = (size_t)bh * SEQ * HD;
    const bf16_t* Qp = Q + base;
    const bf16_t* Vp = V + base + (size_t)pr * 2048 * HD;

    unsigned char* pairBase = smem + pr * 32768;

    // K DMA swizzled source pointers: wave w stages tile rows [w*32, w*32+32)
    const bf16_t* Kpb = K + base + (size_t)pr * 2048 * HD;
    int srcOff = w * 4096 + ((lane >> 3) * 128) +
                 (((lane & 7) ^ ((lane >> 3) & 3)) * 16);
    const bf16_t* kE = (const bf16_t*)((const unsigned char*)Kpb + srcOff);
    const bf16_t* kO = (const bf16_t*)((const unsigned char*)Kpb + (srcOff ^ 64));

    bf16x8 qf[4][2];
#pragma unroll
    for (int qt = 0; qt < 4; qt++)
#pragma unroll
        for (int ks = 0; ks < 2; ks++)
            qf[qt][ks] = ld8(Qp + (size_t)(qw + qt * 16 + c) * HD + ks * 32 + quad * 8);

    f32x4 acc[4][4];
#pragma unroll
    for (int qt = 0; qt < 4; qt++)
#pragma unroll
        for (int dt = 0; dt < 4; dt++) acc[qt][dt] = f32x4{0.f, 0.f, 0.f, 0.f};
    f32x4 accl[4];
#pragma unroll
    for (int qt = 0; qt < 4; qt++) accl[qt] = f32x4{0.f, 0.f, 0.f, 0.f};
    bf16x8 onesv;
#pragma unroll
    for (int j = 0; j < 8; j++) onesv[j] = (bf16_t)1.0f;

    // V staging (pair's 128 threads): rows kva..kva+3, d in [dc8, dc8+8)
    const int tp = t & 127;
    const int kva = 4 * (tp & 15);
    const int dc8 = 8 * (tp >> 4);

    // pre-loop: V tile 0 into regs (issued first), K tile 0 DMA into buf0
    bf16x8 vr0 = ld8(Vp + (size_t)(kva + 0) * HD + dc8);
    bf16x8 vr1 = ld8(Vp + (size_t)(kva + 1) * HD + dc8);
    bf16x8 vr2 = ld8(Vp + (size_t)(kva + 2) * HD + dc8);
    bf16x8 vr3 = ld8(Vp + (size_t)(kva + 3) * HD + dc8);
    {
        bf16_t* dst = (bf16_t*)(pairBase + w * 4096);
#pragma unroll
        for (int i = 0; i < 4; i++)
            gl_lds16(((i & 1) ? kO : kE) + i * 512, dst + i * 512);
        kE += 4096; kO += 4096;
    }

    for (int kt = 0; kt < 32; kt++) {
        uint32_t* vt = (uint32_t*)(pairBase + 16384 + (kt & 1) * 8192);

        // V transpose+swizzle stage for tile kt: one b64 per d row
#pragma unroll
        for (int j = 0; j < 8; j++) {
            int d = dc8 + j;
            int sv = (d & 7) ^ ((d >> 3) & 7);
            int col = ((((kva >> 3) ^ sv) & 7) << 2) + ((kva >> 1) & 3);
            uint2 u;
            u.x = pack2(vr0[j], vr1[j]);     // kv kva, kva+1
            u.y = pack2(vr2[j], vr3[j]);     // kv kva+2, kva+3
            *reinterpret_cast<uint2*>(&vt[d * 32 + col]) = u;
        }

        __syncthreads();   // drains K-DMA(kt), V writes visible, prev readers done

        // prefetch tile kt+1: V into regs FIRST (so next V-write waits
        // vmcnt(4), not 0), then K via DMA into other buf
        if (kt + 1 < 32) {
            int kv0n = (kt + 1) * 64;
            vr0 = ld8(Vp + (size_t)(kv0n + kva + 0) * HD + dc8);
            vr1 = ld8(Vp + (size_t)(kv0n + kva + 1) * HD + dc8);
            vr2 = ld8(Vp + (size_t)(kv0n + kva + 2) * HD + dc8);
            vr3 = ld8(Vp + (size_t)(kv0n + kva + 3) * HD + dc8);
            bf16_t* dst = (bf16_t*)(pairBase + ((kt + 1) & 1) * 8192 + w * 4096);
#pragma unroll
            for (int i = 0; i < 4; i++)
                gl_lds16(((i & 1) ? kO : kE) + i * 512, dst + i * 512);
            kE += 4096; kO += 4096;
        }

        const uint4* kl = (const uint4*)(pairBase + (kt & 1) * 8192);

        // S^T = K*Q^T, kv-permuted rows
        f32x4 st[4][4];
        __builtin_amdgcn_s_setprio(1);
#pragma unroll
        for (int n = 0; n < 4; n++) {
            int kvr = (n >> 1) * 32 + ((c >> 2) * 8) + ((n & 1) * 4) + (c & 3);
            int sk = (kvr & 3) | (((kvr >> 3) & 1) << 2);
            bf16x8 k0 = *reinterpret_cast<const bf16x8*>(&kl[kvr * 8 + (quad ^ sk)]);
            bf16x8 k1 = *reinterpret_cast<const bf16x8*>(&kl[kvr * 8 + ((4 + quad) ^ sk)]);
#pragma unroll
            for (int qt = 0; qt < 4; qt++) {
                f32x4 z = f32x4{0.f, 0.f, 0.f, 0.f};
                z = mfma16(k0, qf[qt][0], z);
                z = mfma16(k1, qf[qt][1], z);
                st[qt][n] = z;
            }
        }
        __builtin_amdgcn_s_setprio(0);

        // softmax without max-subtraction (exp2 domain); no scalar row-sum —
        // the sum rides the MFMA pipe below (ones-MFMA into accl)
        bf16x8 pf[4][2];
#pragma unroll
        for (int qt = 0; qt < 4; qt++) {
            bf16x8 f0, f1;
#pragma unroll
            for (int j = 0; j < 8; j++) {
                f0[j] = (bf16_t)__builtin_amdgcn_exp2f(st[qt][(j >> 2)][j & 3]);
                f1[j] = (bf16_t)__builtin_amdgcn_exp2f(st[qt][2 + (j >> 2)][j & 3]);
            }
            pf[qt][0] = f0;
            pf[qt][1] = f1;
        }

        // O^T += V^T * P^T ; accl += ones * P^T (row-sum on MFMA pipe)
        __builtin_amdgcn_s_setprio(1);
#pragma unroll
        for (int dt = 0; dt < 4; dt++) {
            int d = dt * 16 + c;
            int sv = (d & 7) ^ ((d >> 3) & 7);
            bf16x8 v0f = *reinterpret_cast<const bf16x8*>(&vt[d * 32 + ((quad ^ sv) & 7) * 4]);
            bf16x8 v1f = *reinterpret_cast<const bf16x8*>(&vt[d * 32 + (((4 + quad) ^ sv) & 7) * 4]);
#pragma unroll
            for (int qt = 0; qt < 4; qt++) {
                acc[qt][dt] = mfma16(v0f, pf[qt][0], acc[qt][dt]);
                acc[qt][dt] = mfma16(v1f, pf[qt][1], acc[qt][dt]);
            }
        }
#pragma unroll
        for (int qt = 0; qt < 4; qt++) {
            accl[qt] = mfma16(onesv, pf[qt][0], accl[qt]);
            accl[qt] = mfma16(onesv, pf[qt][1], accl[qt]);
        }
        __builtin_amdgcn_s_setprio(0);
    }

    // every row of accl[qt] equals the kv-sum for q col c: no shfl needed
    float lred[4];
#pragma unroll
    for (int qt = 0; qt < 4; qt++) lred[qt] = accl[qt][0];

    // in-block pair-combine via LDS overlay
    __syncthreads();
    float* Ox = (float*)smem;
    float* Lx = (float*)(smem + 128 * 68 * 4);

    if (pr == 1) {
#pragma unroll
        for (int qt = 0; qt < 4; qt++) {
            int ql = w * 64 + qt * 16 + c;
#pragma unroll
            for (int dt = 0; dt < 4; dt++)
                *reinterpret_cast<f32x4*>(&Ox[ql * 68 + dt * 16 + quad * 4]) = acc[qt][dt];
            if (quad == 0) Lx[ql] = lred[qt];
        }
    }
    __syncthreads();
    if (pr == 0) {
        int b_ = bh >> 3, h = bh & 7;
#pragma unroll
        for (int qt = 0; qt < 4; qt++) {
            int ql = w * 64 + qt * 16 + c;
            float inv_l = 1.0f / (lred[qt] + Lx[ql]);
            int srow = qw + qt * 16 + c;
            bf16_t* yrow = Y + (size_t)(b_ * SEQ + srow) * DMODEL + h * HD;
#pragma unroll
            for (int dt = 0; dt < 4; dt++) {
                f32x4 o4 = acc[qt][dt] + *reinterpret_cast<const f32x4*>(&Ox[ql * 68 + dt * 16 + quad * 4]);
                bf16x4 o;
#pragma unroll
                for (int r = 0; r < 4; r++) o[r] = (bf16_t)(o4[r] * inv_l);
                *reinterpret_cast<bf16x4*>(yrow + dt * 16 + quad * 4) = o;
            }
        }
    }
}

extern "C" void kernel_launch(void* const* d_in, const int* in_sizes, int n_in,
                              void* d_out, int out_size, void* d_ws, size_t ws_size,
                              hipStream_t stream) {
    (void)in_sizes; (void)n_in; (void)out_size; (void)ws_size;
    const float* x  = (const float*)d_in[0];
    const float* Wq = (const float*)d_in[1];
    const float* Wk = (const float*)d_in[2];
    const float* Wv = (const float*)d_in[3];
    const float* Wo = (const float*)d_in[4];
    const int*   Vp = (const int*)d_in[6];
    float* out = (float*)d_out;

    bf16_t* ws  = (bf16_t*)d_ws;
    bf16_t* Wc  = ws;                    // [Wq|Wk|Wv] 3*512*512
    bf16_t* Wob = Wc  + 786432;          // 512*512
    bf16_t* Qb  = Wob + 262144;
    bf16_t* Kb  = Qb  + 4194304;
    bf16_t* Vb  = Kb  + 4194304;
    bf16_t* Yb  = Vb  + 4194304;
    // RoPE table overlays Yb (dead until flash_attn writes Y): 4096*32*8 B = 1 MB
    float2* tab = (float2*)Yb;

    cast_w<<<1024, 256, 0, stream>>>(Wq, Wk, Wv, Wo, Wc, Wob, tab, Vp);

    // r24: m-fast grids restored (r23 n-fast swap cost ~13 us)
    gemm_qkv<<<dim3(64, 12), 256, 0, stream>>>(x, Wc, Qb, Kb, Vb, tab);

    flash_attn<<<512, 256, 0, stream>>>(Qb, Kb, Vb, Yb);

    gemm_out<<<dim3(64, 8), 256, 0, stream>>>(Yb, Wob, out);
}